// Round 1
// baseline (252.093 us; speedup 1.0000x reference)
//
#include <hip/hip_runtime.h>
#include <hip/hip_bf16.h>

// Retention: out = (tril(alpha^(i-j)) * (QK^T/sqrt(d))) @ V, qkv = x@W + b
// B=16, S=1024, D=768. Decay folded into operands:
//   Q' = (q)*alpha^i/sqrt(d), K' = (k)*alpha^(-j)  ->  masked scores = tril(Q'K'^T)

#define SEQ   1024
#define DIM   768
#define ND3   2304
#define GROUP 8

typedef __attribute__((ext_vector_type(8))) short bf16x8;
typedef __attribute__((ext_vector_type(4))) float f32x4;

#define L2A     (-0.014499569695115089f)   // log2(0.99)
#define RSQRTD  (0.03608439182435161f)     // 1/sqrt(768)

__device__ __forceinline__ unsigned short f2bf(float x) {
  union { float f; unsigned u; } v; v.f = x;
  unsigned r = v.u + 0x7FFFu + ((v.u >> 16) & 1u);
  return (unsigned short)(r >> 16);
}

// ---------------- W transpose+convert: W[768][2304] f32 -> Wt[2304][768] bf16
__global__ void transpose_w(const float* __restrict__ W, unsigned short* __restrict__ Wt) {
  __shared__ float tile[64][65];
  int n0 = (blockIdx.x % 36) * 64;
  int k0 = (blockIdx.x / 36) * 64;
  int tx = threadIdx.x & 63, ty = threadIdx.x >> 6;   // 256 thr: 64 x 4
#pragma unroll
  for (int p = 0; p < 16; ++p) {
    int k = ty + p * 4;
    tile[k][tx] = W[(size_t)(k0 + k) * ND3 + n0 + tx];
  }
  __syncthreads();
#pragma unroll
  for (int p = 0; p < 16; ++p) {
    int n = ty + p * 4;
    Wt[(size_t)(n0 + n) * DIM + k0 + tx] = f2bf(tile[tx][n]);
  }
}

// ---------------- QKV GEMM: x[16384][768] (f32, cast inline) @ Wt^T -> Q',K',Vt
// 128x128 tile, BK=64, 4 waves (2x2), each wave 64x64 = 4x4 16x16 frags.
__global__ void __launch_bounds__(256) qkv_gemm(
    const float* __restrict__ x, const unsigned short* __restrict__ Wt,
    const float* __restrict__ bias,
    unsigned short* __restrict__ Qs, unsigned short* __restrict__ Ks,
    unsigned short* __restrict__ Vt) {
  __shared__ short lsA[128 * 72];
  __shared__ short lsB[128 * 72];
  int nt = blockIdx.x % 18, mt = blockIdx.x / 18;
  int m0 = mt * 128, n0 = nt * 128;
  int tid = threadIdx.x;
  int lane = tid & 63, wid = tid >> 6;
  int wr = wid >> 1, wc = wid & 1;
  int lr = lane & 15, lg = lane >> 4;

  f32x4 acc[4][4] = {};

  for (int k0 = 0; k0 < DIM; k0 += 64) {
#pragma unroll
    for (int itr = 0; itr < 4; ++itr) {
      int c = itr * 256 + tid;
      int row = c >> 3, kc = (c & 7) << 3;
      const float* p = x + (size_t)(m0 + row) * DIM + k0 + kc;
      float4 f0 = *(const float4*)p;
      float4 f1 = *(const float4*)(p + 4);
      bf16x8 v;
      v[0] = (short)f2bf(f0.x); v[1] = (short)f2bf(f0.y);
      v[2] = (short)f2bf(f0.z); v[3] = (short)f2bf(f0.w);
      v[4] = (short)f2bf(f1.x); v[5] = (short)f2bf(f1.y);
      v[6] = (short)f2bf(f1.z); v[7] = (short)f2bf(f1.w);
      *(bf16x8*)&lsA[row * 72 + kc] = v;
      *(bf16x8*)&lsB[row * 72 + kc] =
          *(const bf16x8*)(Wt + (size_t)(n0 + row) * DIM + k0 + kc);
    }
    __syncthreads();
#pragma unroll
    for (int ks = 0; ks < 64; ks += 32) {
      bf16x8 af[4], bfr[4];
#pragma unroll
      for (int m = 0; m < 4; ++m)
        af[m] = *(const bf16x8*)&lsA[(wr * 64 + m * 16 + lr) * 72 + ks + lg * 8];
#pragma unroll
      for (int n = 0; n < 4; ++n)
        bfr[n] = *(const bf16x8*)&lsB[(wc * 64 + n * 16 + lr) * 72 + ks + lg * 8];
#pragma unroll
      for (int m = 0; m < 4; ++m)
#pragma unroll
        for (int n = 0; n < 4; ++n)
          acc[m][n] = __builtin_amdgcn_mfma_f32_16x16x32_bf16(af[m], bfr[n], acc[m][n], 0, 0, 0);
    }
    __syncthreads();
  }

#pragma unroll
  for (int m = 0; m < 4; ++m)
#pragma unroll
    for (int n = 0; n < 4; ++n) {
      int ng = n0 + wc * 64 + n * 16 + lr;
      float bia = bias[ng];
#pragma unroll
      for (int r = 0; r < 4; ++r) {
        int mg = m0 + wr * 64 + m * 16 + lg * 4 + r;
        float val = acc[m][n][r] + bia;
        int b = mg >> 10, s = mg & 1023;
        if (ng < DIM) {
          float sc = exp2f((float)s * L2A) * RSQRTD;
          Qs[((size_t)b * SEQ + s) * DIM + ng] = f2bf(val * sc);
        } else if (ng < 2 * DIM) {
          float sc = exp2f(-(float)s * L2A);
          Ks[((size_t)b * SEQ + s) * DIM + (ng - DIM)] = f2bf(val * sc);
        } else {
          Vt[((size_t)b * DIM + (ng - 2 * DIM)) * SEQ + s] = f2bf(val);
        }
      }
    }
}

// ---------------- scores: Sm[bl][i][j] = tril(Q'[b] @ K'[b]^T), bf16
// only lower-triangular 128-tiles (36 per batch)
__global__ void __launch_bounds__(256) score_gemm(
    const unsigned short* __restrict__ Qs, const unsigned short* __restrict__ Ks,
    unsigned short* __restrict__ Sm, int b_base) {
  __shared__ short lsA[128 * 72];
  __shared__ short lsB[128 * 72];
  int t = blockIdx.x % 36;
  int bl = blockIdx.x / 36;
  int b = b_base + bl;
  int it = 0;
  while (t >= it + 1) { t -= it + 1; it++; }
  int jt = t;
  int m0 = it * 128, n0 = jt * 128;
  const unsigned short* A  = Qs + (size_t)b * SEQ * DIM;
  const unsigned short* Bt = Ks + (size_t)b * SEQ * DIM;
  unsigned short* Smp = Sm + (size_t)bl * SEQ * SEQ;

  int tid = threadIdx.x;
  int lane = tid & 63, wid = tid >> 6;
  int wr = wid >> 1, wc = wid & 1;
  int lr = lane & 15, lg = lane >> 4;

  f32x4 acc[4][4] = {};

  for (int k0 = 0; k0 < DIM; k0 += 64) {
#pragma unroll
    for (int itr = 0; itr < 4; ++itr) {
      int c = itr * 256 + tid;
      int row = c >> 3, kc = (c & 7) << 3;
      *(bf16x8*)&lsA[row * 72 + kc] =
          *(const bf16x8*)(A + (size_t)(m0 + row) * DIM + k0 + kc);
      *(bf16x8*)&lsB[row * 72 + kc] =
          *(const bf16x8*)(Bt + (size_t)(n0 + row) * DIM + k0 + kc);
    }
    __syncthreads();
#pragma unroll
    for (int ks = 0; ks < 64; ks += 32) {
      bf16x8 af[4], bfr[4];
#pragma unroll
      for (int m = 0; m < 4; ++m)
        af[m] = *(const bf16x8*)&lsA[(wr * 64 + m * 16 + lr) * 72 + ks + lg * 8];
#pragma unroll
      for (int n = 0; n < 4; ++n)
        bfr[n] = *(const bf16x8*)&lsB[(wc * 64 + n * 16 + lr) * 72 + ks + lg * 8];
#pragma unroll
      for (int m = 0; m < 4; ++m)
#pragma unroll
        for (int n = 0; n < 4; ++n)
          acc[m][n] = __builtin_amdgcn_mfma_f32_16x16x32_bf16(af[m], bfr[n], acc[m][n], 0, 0, 0);
    }
    __syncthreads();
  }

#pragma unroll
  for (int m = 0; m < 4; ++m)
#pragma unroll
    for (int n = 0; n < 4; ++n) {
      int j = n0 + wc * 64 + n * 16 + lr;
#pragma unroll
      for (int r = 0; r < 4; ++r) {
        int i = m0 + wr * 64 + m * 16 + lg * 4 + r;
        float v = acc[m][n][r];
        if (j > i) v = 0.0f;   // causal mask (only bites on diagonal tiles)
        Smp[(size_t)i * SEQ + j] = f2bf(v);
      }
    }
}

// ---------------- PV: out[b][i][d] = Sm[bl] @ V[b];  Bt = Vt[b] [d][j]
// K-loop bounded causally: j < (it+1)*128
__global__ void __launch_bounds__(256) pv_gemm(
    const unsigned short* __restrict__ Sm, const unsigned short* __restrict__ Vt,
    float* __restrict__ out, int b_base) {
  __shared__ short lsA[128 * 72];
  __shared__ short lsB[128 * 72];
  int idx = blockIdx.x % 48;
  int bl = blockIdx.x / 48;
  int b = b_base + bl;
  int it = idx / 6, nt = idx % 6;
  int m0 = it * 128, n0 = nt * 128;
  const unsigned short* A  = Sm + (size_t)bl * SEQ * SEQ;   // ld = 1024
  const unsigned short* Bt = Vt + (size_t)b * DIM * SEQ;    // ld = 1024
  int kmax = (it + 1) * 128;

  int tid = threadIdx.x;
  int lane = tid & 63, wid = tid >> 6;
  int wr = wid >> 1, wc = wid & 1;
  int lr = lane & 15, lg = lane >> 4;

  f32x4 acc[4][4] = {};

  for (int k0 = 0; k0 < kmax; k0 += 64) {
#pragma unroll
    for (int itr = 0; itr < 4; ++itr) {
      int c = itr * 256 + tid;
      int row = c >> 3, kc = (c & 7) << 3;
      *(bf16x8*)&lsA[row * 72 + kc] =
          *(const bf16x8*)(A + (size_t)(m0 + row) * SEQ + k0 + kc);
      *(bf16x8*)&lsB[row * 72 + kc] =
          *(const bf16x8*)(Bt + (size_t)(n0 + row) * SEQ + k0 + kc);
    }
    __syncthreads();
#pragma unroll
    for (int ks = 0; ks < 64; ks += 32) {
      bf16x8 af[4], bfr[4];
#pragma unroll
      for (int m = 0; m < 4; ++m)
        af[m] = *(const bf16x8*)&lsA[(wr * 64 + m * 16 + lr) * 72 + ks + lg * 8];
#pragma unroll
      for (int n = 0; n < 4; ++n)
        bfr[n] = *(const bf16x8*)&lsB[(wc * 64 + n * 16 + lr) * 72 + ks + lg * 8];
#pragma unroll
      for (int m = 0; m < 4; ++m)
#pragma unroll
        for (int n = 0; n < 4; ++n)
          acc[m][n] = __builtin_amdgcn_mfma_f32_16x16x32_bf16(af[m], bfr[n], acc[m][n], 0, 0, 0);
    }
    __syncthreads();
  }

#pragma unroll
  for (int m = 0; m < 4; ++m)
#pragma unroll
    for (int n = 0; n < 4; ++n) {
      int ng = n0 + wc * 64 + n * 16 + lr;
#pragma unroll
      for (int r = 0; r < 4; ++r) {
        int mg = m0 + wr * 64 + m * 16 + lg * 4 + r;
        out[((size_t)b * SEQ + mg) * DIM + ng] = acc[m][n][r];
      }
    }
}

extern "C" void kernel_launch(void* const* d_in, const int* in_sizes, int n_in,
                              void* d_out, int out_size, void* d_ws, size_t ws_size,
                              hipStream_t stream) {
  const float* x    = (const float*)d_in[0];
  const float* W    = (const float*)d_in[1];
  const float* bias = (const float*)d_in[2];
  float* out = (float*)d_out;

  char* ws = (char*)d_ws;
  // ws layout (bytes):
  //   Wt : 2304*768*2      =  3,538,944
  //   Qs : 16*1024*768*2   = 25,165,824
  //   Ks : 25,165,824
  //   Vt : 16*768*1024*2   = 25,165,824
  //   Sm : 8*1024*1024*2   = 16,777,216   (reused across 2 batch-groups)
  unsigned short* Wt = (unsigned short*)(ws);
  unsigned short* Qs = (unsigned short*)(ws + 3538944);
  unsigned short* Ks = (unsigned short*)(ws + 3538944 + 25165824);
  unsigned short* Vt = (unsigned short*)(ws + 3538944 + 2 * 25165824);
  unsigned short* Sm = (unsigned short*)(ws + 3538944 + 3 * 25165824);

  transpose_w<<<36 * 12, 256, 0, stream>>>(W, Wt);
  qkv_gemm<<<128 * 18, 256, 0, stream>>>(x, Wt, bias, Qs, Ks, Vt);
  for (int g = 0; g < 2; ++g) {
    score_gemm<<<GROUP * 36, 256, 0, stream>>>(Qs, Ks, Sm, g * GROUP);
    pv_gemm<<<GROUP * 48, 256, 0, stream>>>(Sm, Vt, out, g * GROUP);
  }
}